// Round 1
// baseline (424.565 us; speedup 1.0000x reference)
//
#include <hip/hip_runtime.h>
#include <hip/hip_bf16.h>

// Problem constants (S, B, E, H) = (2048, 2, 1024, 16), HD = 64
#define S_LEN 2048
#define BATCH 2
#define EMB   1024
#define NH    16
#define HDIM  64
#define MROWS (S_LEN * BATCH)   // 4096 rows of the (S,B,E) matrices

typedef _Float16 half4v __attribute__((ext_vector_type(4)));
typedef _Float16 half8v __attribute__((ext_vector_type(8)));
typedef float    f32x4  __attribute__((ext_vector_type(4)));

static __device__ __forceinline__ half8v join44(half4v lo, half4v hi) {
  half8v r;
  r[0] = lo[0]; r[1] = lo[1]; r[2] = lo[2]; r[3] = lo[3];
  r[4] = hi[0]; r[5] = hi[1]; r[6] = hi[2]; r[7] = hi[3];
  return r;
}

// ---------------------------------------------------------------------------
// TN GEMM: C[M,N] = A[M,K] @ W[N,K]^T + bias[N]
// A, W are f32 row-major (K contiguous for both). f32->f16 convert in staging.
// MODE 0: write f32 row-major to dst (out-projection -> d_out).
// MODE 1: write f16 to (B,H,S,HD) head-layout buffer (in-projection).
// Tile 64x64, BK=32, 256 threads (4 waves, each 32x32 via 2x2 MFMA frags).
// ---------------------------------------------------------------------------
template <int MODE>
__global__ __launch_bounds__(256) void gemm_tn(const float* __restrict__ A,
                                               const float* __restrict__ W,
                                               const float* __restrict__ bias,
                                               void* __restrict__ dstv,
                                               int M, int N, int K) {
  __shared__ __align__(16) _Float16 At[64][40];  // +8 pad: conflict-light
  __shared__ __align__(16) _Float16 Wt[64][40];

  const int tid = threadIdx.x;
  const int lane = tid & 63;
  const int w = tid >> 6;          // wave 0..3
  const int g = lane >> 4;         // 16-lane group 0..3
  const int r16 = lane & 15;
  const int bm = blockIdx.y * 64;
  const int bn = blockIdx.x * 64;
  const int wr = (w >> 1) * 32;    // wave row offset in tile
  const int wc = (w & 1) * 32;     // wave col offset in tile
  const int sr = tid >> 2;         // staging row 0..63
  const int sc = (tid & 3) * 8;    // staging col 0..31 step 8

  f32x4 acc[2][2];
#pragma unroll
  for (int m = 0; m < 2; m++)
#pragma unroll
    for (int n = 0; n < 2; n++) acc[m][n] = (f32x4){0.f, 0.f, 0.f, 0.f};

  const float* ap = A + (size_t)(bm + sr) * K + sc;
  const float* wp = W + (size_t)(bn + sr) * K + sc;

  for (int k0 = 0; k0 < K; k0 += 32) {
    float4 a0 = *(const float4*)(ap + k0);
    float4 a1 = *(const float4*)(ap + k0 + 4);
    float4 w0 = *(const float4*)(wp + k0);
    float4 w1 = *(const float4*)(wp + k0 + 4);
    half8v av, wv;
    av[0] = (_Float16)a0.x; av[1] = (_Float16)a0.y;
    av[2] = (_Float16)a0.z; av[3] = (_Float16)a0.w;
    av[4] = (_Float16)a1.x; av[5] = (_Float16)a1.y;
    av[6] = (_Float16)a1.z; av[7] = (_Float16)a1.w;
    wv[0] = (_Float16)w0.x; wv[1] = (_Float16)w0.y;
    wv[2] = (_Float16)w0.z; wv[3] = (_Float16)w0.w;
    wv[4] = (_Float16)w1.x; wv[5] = (_Float16)w1.y;
    wv[6] = (_Float16)w1.z; wv[7] = (_Float16)w1.w;

    __syncthreads();  // previous iteration's frag reads done
    *(half8v*)&At[sr][sc] = av;
    *(half8v*)&Wt[sr][sc] = wv;
    __syncthreads();

    half8v af[2], bf[2];
#pragma unroll
    for (int m = 0; m < 2; m++) {
      const _Float16* p = &At[wr + m * 16 + r16][g * 4];
      af[m] = join44(*(const half4v*)p, *(const half4v*)(p + 16));
    }
#pragma unroll
    for (int n = 0; n < 2; n++) {
      const _Float16* p = &Wt[wc + n * 16 + r16][g * 4];
      bf[n] = join44(*(const half4v*)p, *(const half4v*)(p + 16));
    }
#pragma unroll
    for (int m = 0; m < 2; m++)
#pragma unroll
      for (int n = 0; n < 2; n++)
        acc[m][n] = __builtin_amdgcn_mfma_f32_16x16x32_f16(af[m], bf[n],
                                                           acc[m][n], 0, 0, 0);
  }

  // Epilogue. C/D frag mapping (verified m89/m91): row = 4*(lane>>4)+reg,
  // col = lane&15.
#pragma unroll
  for (int m = 0; m < 2; m++)
#pragma unroll
    for (int n = 0; n < 2; n++) {
      const int row = bm + wr + m * 16 + g * 4;
      const int col = bn + wc + n * 16 + r16;
      const float bcol = bias[col];
#pragma unroll
      for (int r = 0; r < 4; r++) {
        const float v = acc[m][n][r] + bcol;
        const int rr = row + r;
        if (MODE == 0) {
          ((float*)dstv)[(size_t)rr * N + col] = v;
        } else {
          // rr = s*BATCH + b ; col = h*64 + d  ->  (B,H,S,HD)
          const int s = rr >> 1, b = rr & 1;
          const int h = col >> 6, d = col & 63;
          ((_Float16*)dstv)[(((size_t)(b * NH + h)) * S_LEN + s) * HDIM + d] =
              (_Float16)v;
        }
      }
    }
}

// ---------------------------------------------------------------------------
// Row L2-normalize (per 64-wide head row), optionally folding 1/clip(tau,.01).
// One wave per row; 4 rows per 256-thread block.
// ---------------------------------------------------------------------------
__global__ __launch_bounds__(256) void norm_rows(_Float16* __restrict__ buf,
                                                 const float* __restrict__ tau,
                                                 int use_tau) {
  const int row = blockIdx.x * 4 + (threadIdx.x >> 6);
  const int lane = threadIdx.x & 63;
  const size_t idx = (size_t)row * HDIM + lane;
  const float v = (float)buf[idx];
  float ss = v * v;
#pragma unroll
  for (int m = 1; m < 64; m <<= 1) ss += __shfl_xor(ss, m, 64);
  float scale = 1.0f / fmaxf(sqrtf(ss), 1e-12f);
  if (use_tau) {
    const int h = (row >> 11) & (NH - 1);  // row = (b*NH+h)*S + s
    scale *= 1.0f / fmaxf(tau[h], 0.01f);
  }
  buf[idx] = (_Float16)(v * scale);
}

// ---------------------------------------------------------------------------
// Flash attention, one (b,h) head + 64-row Q tile per block, 4 waves x 16 rows.
// KV tile = 64. qn has 1/tau folded in; qn/kn L2-normalized.
// ---------------------------------------------------------------------------
__global__ __launch_bounds__(256) void attn_fwd(const _Float16* __restrict__ qn,
                                                const _Float16* __restrict__ kn,
                                                const _Float16* __restrict__ vv,
                                                float* __restrict__ outp) {
  __shared__ __align__(16) _Float16 Kt[64][72];      // [key][d]
  __shared__ __align__(16) _Float16 Vt[64][72];      // [d][key] (transposed)
  __shared__ __align__(16) _Float16 Pt[4][16][72];   // per-wave P tile

  const int tid = threadIdx.x;
  const int lane = tid & 63;
  const int w = tid >> 6;
  const int g = lane >> 4;
  const int r16 = lane & 15;
  const int bh = blockIdx.y;           // b*NH + h
  const int b = bh >> 4, h = bh & 15;
  const int q0 = blockIdx.x * 64;

  const size_t hb = (size_t)bh * S_LEN * HDIM;
  const _Float16* Q = qn + hb;
  const _Float16* Kp = kn + hb;
  const _Float16* Vp = vv + hb;

  // Q fragments for this wave's 16 rows (held in registers for whole kernel)
  half8v qf[2];
  {
    const _Float16* qp = Q + (size_t)(q0 + w * 16 + r16) * HDIM;
#pragma unroll
    for (int kk = 0; kk < 2; kk++) {
      half4v lo = *(const half4v*)(qp + kk * 32 + g * 4);
      half4v hi = *(const half4v*)(qp + kk * 32 + 16 + g * 4);
      qf[kk] = join44(lo, hi);
    }
  }

  f32x4 o[4];
#pragma unroll
  for (int n = 0; n < 4; n++) o[n] = (f32x4){0.f, 0.f, 0.f, 0.f};
  float mrow[4] = {-1e30f, -1e30f, -1e30f, -1e30f};
  float lrow[4] = {0.f, 0.f, 0.f, 0.f};

  const int skey = tid >> 2;        // staging key row 0..63
  const int sd = (tid & 3) * 16;    // staging d base

  for (int t0 = 0; t0 < S_LEN; t0 += 64) {
    __syncthreads();  // all waves done reading Kt/Vt/Pt of prev tile
    {
      const _Float16* kp = Kp + (size_t)(t0 + skey) * HDIM + sd;
      half8v k0v = *(const half8v*)(kp);
      half8v k1v = *(const half8v*)(kp + 8);
      *(half8v*)&Kt[skey][sd] = k0v;
      *(half8v*)&Kt[skey][sd + 8] = k1v;
      const _Float16* vp = Vp + (size_t)(t0 + skey) * HDIM + sd;
      half8v v0v = *(const half8v*)(vp);
      half8v v1v = *(const half8v*)(vp + 8);
#pragma unroll
      for (int j = 0; j < 8; j++) {
        Vt[sd + j][skey] = v0v[j];
        Vt[sd + 8 + j][skey] = v1v[j];
      }
    }
    __syncthreads();

    // S = Q @ K^T  (16 x 64 per wave)
    f32x4 sv[4];
#pragma unroll
    for (int n = 0; n < 4; n++) {
      sv[n] = (f32x4){0.f, 0.f, 0.f, 0.f};
      const _Float16* kb = &Kt[n * 16 + r16][0];
#pragma unroll
      for (int kk = 0; kk < 2; kk++) {
        half4v lo = *(const half4v*)(kb + kk * 32 + g * 4);
        half4v hi = *(const half4v*)(kb + kk * 32 + 16 + g * 4);
        sv[n] = __builtin_amdgcn_mfma_f32_16x16x32_f16(qf[kk], join44(lo, hi),
                                                       sv[n], 0, 0, 0);
      }
    }

    // online softmax (per q-row; row r of frag lives in 16 lanes, reg r%4)
    float pm[4];
#pragma unroll
    for (int r = 0; r < 4; r++) {
      float t = fmaxf(fmaxf(sv[0][r], sv[1][r]), fmaxf(sv[2][r], sv[3][r]));
      t = fmaxf(t, __shfl_xor(t, 1, 64));
      t = fmaxf(t, __shfl_xor(t, 2, 64));
      t = fmaxf(t, __shfl_xor(t, 4, 64));
      t = fmaxf(t, __shfl_xor(t, 8, 64));
      pm[r] = t;
    }
    float sc[4];
#pragma unroll
    for (int r = 0; r < 4; r++) {
      const float mn = fmaxf(mrow[r], pm[r]);
      sc[r] = __expf(mrow[r] - mn);
      mrow[r] = mn;
    }
    float ps[4] = {0.f, 0.f, 0.f, 0.f};
#pragma unroll
    for (int n = 0; n < 4; n++)
#pragma unroll
      for (int r = 0; r < 4; r++) {
        const float p = __expf(sv[n][r] - mrow[r]);
        sv[n][r] = p;
        ps[r] += p;
      }
#pragma unroll
    for (int r = 0; r < 4; r++) {
      float t = ps[r];
      t += __shfl_xor(t, 1, 64);
      t += __shfl_xor(t, 2, 64);
      t += __shfl_xor(t, 4, 64);
      t += __shfl_xor(t, 8, 64);
      lrow[r] = lrow[r] * sc[r] + t;
    }
#pragma unroll
    for (int n = 0; n < 4; n++)
#pragma unroll
      for (int r = 0; r < 4; r++) o[n][r] *= sc[r];

    // P (C-frag layout) -> per-wave LDS as [row][key] f16
#pragma unroll
    for (int n = 0; n < 4; n++)
#pragma unroll
      for (int r = 0; r < 4; r++)
        Pt[w][g * 4 + r][n * 16 + r16] = (_Float16)sv[n][r];
    __syncthreads();

    // O += P @ V
#pragma unroll
    for (int kk = 0; kk < 2; kk++) {
      const _Float16* pb = &Pt[w][r16][kk * 32];
      half8v pf = join44(*(const half4v*)(pb + g * 4),
                         *(const half4v*)(pb + 16 + g * 4));
#pragma unroll
      for (int n = 0; n < 4; n++) {
        const _Float16* vb = &Vt[n * 16 + r16][kk * 32];
        half8v vf = join44(*(const half4v*)(vb + g * 4),
                           *(const half4v*)(vb + 16 + g * 4));
        o[n] = __builtin_amdgcn_mfma_f32_16x16x32_f16(pf, vf, o[n], 0, 0, 0);
      }
    }
  }

  // write attention output as f32 (S,B,E) for the out-projection GEMM
#pragma unroll
  for (int n = 0; n < 4; n++)
#pragma unroll
    for (int r = 0; r < 4; r++) {
      const int srow = q0 + w * 16 + g * 4 + r;
      const int e = h * HDIM + n * 16 + r16;
      outp[((size_t)srow * BATCH + b) * EMB + e] = o[n][r] / lrow[r];
    }
}

// ---------------------------------------------------------------------------
extern "C" void kernel_launch(void* const* d_in, const int* in_sizes, int n_in,
                              void* d_out, int out_size, void* d_ws,
                              size_t ws_size, hipStream_t stream) {
  const float* query = (const float*)d_in[0];
  const float* key   = (const float*)d_in[1];
  const float* value = (const float*)d_in[2];
  const float* ipw   = (const float*)d_in[3];  // (3E, E)
  const float* ipb   = (const float*)d_in[4];  // (3E,)
  const float* opw   = (const float*)d_in[5];  // (E, E)
  const float* opb   = (const float*)d_in[6];  // (E,)
  const float* tau   = (const float*)d_in[7];  // (1,H,1,1)

  // workspace layout (all fully rewritten every call)
  _Float16* qbuf = (_Float16*)d_ws;                       // (B,H,S,HD) f16
  _Float16* kbuf = qbuf + (size_t)MROWS * EMB;
  _Float16* vbuf = kbuf + (size_t)MROWS * EMB;
  float* abuf = (float*)(vbuf + (size_t)MROWS * EMB);     // (S,B,E) f32

  const dim3 blk(256);
  const dim3 gg(EMB / 64, MROWS / 64);  // 16 x 64

  gemm_tn<1><<<gg, blk, 0, stream>>>(query, ipw, ipb, qbuf, MROWS, EMB, EMB);
  gemm_tn<1><<<gg, blk, 0, stream>>>(key, ipw + (size_t)EMB * EMB, ipb + EMB,
                                     kbuf, MROWS, EMB, EMB);
  gemm_tn<1><<<gg, blk, 0, stream>>>(value, ipw + 2 * (size_t)EMB * EMB,
                                     ipb + 2 * EMB, vbuf, MROWS, EMB, EMB);

  const int nrows = BATCH * NH * S_LEN;  // 65536
  norm_rows<<<nrows / 4, blk, 0, stream>>>(qbuf, tau, 1);
  norm_rows<<<nrows / 4, blk, 0, stream>>>(kbuf, tau, 0);

  attn_fwd<<<dim3(S_LEN / 64, BATCH * NH), blk, 0, stream>>>(qbuf, kbuf, vbuf,
                                                             abuf);

  gemm_tn<0><<<gg, blk, 0, stream>>>(abuf, opw, opb, d_out, MROWS, EMB, EMB);
}

// Round 3
// 303.023 us; speedup vs baseline: 1.4011x; 1.4011x over previous
//
#include <hip/hip_runtime.h>
#include <hip/hip_bf16.h>

// Problem constants (S, B, E, H) = (2048, 2, 1024, 16), HD = 64
#define S_LEN 2048
#define BATCH 2
#define EMB   1024
#define NH    16
#define HDIM  64
#define MROWS (S_LEN * BATCH)   // 4096 rows of the (S,B,E) matrices

typedef _Float16 half4v __attribute__((ext_vector_type(4)));
typedef _Float16 half8v __attribute__((ext_vector_type(8)));
typedef float    f32x4  __attribute__((ext_vector_type(4)));

static __device__ __forceinline__ half8v join44(half4v lo, half4v hi) {
  half8v r;
  r[0] = lo[0]; r[1] = lo[1]; r[2] = lo[2]; r[3] = lo[3];
  r[4] = hi[0]; r[5] = hi[1]; r[6] = hi[2]; r[7] = hi[3];
  return r;
}

// async global->LDS, 16B per lane. dst must be the wave-uniform base
// (HW adds lane*16); src is per-lane.
static __device__ __forceinline__ void gl_lds16(const _Float16* src, void* dst) {
  __builtin_amdgcn_global_load_lds(
      (const __attribute__((address_space(1))) void*)src,
      (__attribute__((address_space(3))) void*)dst, 16, 0, 0);
}

// ---------------------------------------------------------------------------
// f32 -> f16 convert (weights prepass)
// ---------------------------------------------------------------------------
__global__ __launch_bounds__(256) void cvt4(const float* __restrict__ in,
                                            _Float16* __restrict__ out, int n4) {
  const int i = blockIdx.x * 256 + threadIdx.x;
  if (i < n4) {
    const float4 f = ((const float4*)in)[i];
    half4v hv;
    hv[0] = (_Float16)f.x; hv[1] = (_Float16)f.y;
    hv[2] = (_Float16)f.z; hv[3] = (_Float16)f.w;
    ((half4v*)out)[i] = hv;
  }
}

// ---------------------------------------------------------------------------
// TN GEMM: C[M,N] = A[M,K] @ W[N,K]^T + bias[N], K = EMB = 1024, M tile 128,
// N tile NT (128 or 64), BK = 64. 256 threads, 4 waves, each 64 x NT/2.
// W is f16 (pre-converted), staged via global_load_lds with T2 XOR swizzle
// (colbyte ^= (row&7)<<4, 16B granule -> conflict-free-ish ds_read_b64).
// INPROJ=1: A is f32 (query/key/value selected by blockIdx.z), reg-staged
//           with convert + swizzled ds_write; dst = f16 (B,H,S,HD) buffers.
// INPROJ=0: A is f16 (attn output), staged via global_load_lds; dst = f32.
// ---------------------------------------------------------------------------
template <int INPROJ, int NT>
__global__ __launch_bounds__(256, 3) void gemm_f16(
    const float* __restrict__ Aq, const float* __restrict__ Ak,
    const float* __restrict__ Av, const _Float16* __restrict__ A16,
    const _Float16* __restrict__ Wall, const float* __restrict__ ball,
    void* __restrict__ dstbase) {
  constexpr int NF = NT / 32;  // B-frags per wave
  __shared__ __align__(16) _Float16 As[128 * 64];
  __shared__ __align__(16) _Float16 Bs[NT * 64];

  const int tid = threadIdx.x, lane = tid & 63, w = tid >> 6;
  const int g = lane >> 4, r16 = lane & 15;
  const int z = blockIdx.z;
  const int bm = blockIdx.y * 128, bn = blockIdx.x * NT;
  const int wr = (w >> 1) * 64, wc = (w & 1) * (NT / 2);
  const int swz = (r16 & 7) << 4;

  const float* A32 = (z == 0) ? Aq : (z == 1) ? Ak : Av;
  const _Float16* W = Wall + (size_t)z * EMB * EMB;
  const float* bias = ball + z * EMB;

  f32x4 acc[4][NF];
#pragma unroll
  for (int m = 0; m < 4; m++)
#pragma unroll
    for (int n = 0; n < NF; n++) acc[m][n] = (f32x4){0.f, 0.f, 0.f, 0.f};

  // in-proj A staging coords: thread covers row ar, 32 f32 cols
  const int ar = tid >> 1;
  const int acb = (tid & 1) * 64;        // byte col base within 128B row
  const int ar7 = (ar & 7) << 4;
  const float* ap = nullptr;
  if (INPROJ) ap = A32 + (size_t)(bm + ar) * EMB + (tid & 1) * 32;

  for (int k0 = 0; k0 < EMB; k0 += 64) {
    __syncthreads();
    // B tile: NT rows x 64 halves (128B/row), swizzled via pre-swizzled src
#pragma unroll
    for (int i = 0; i < NF; i++) {
      const int doff = w * (NF * 1024) + i * 1024 + lane * 16;
      const int row = doff >> 7;
      const int colh = ((doff & 127) ^ ((row & 7) << 4)) >> 1;
      gl_lds16(W + (size_t)(bn + row) * EMB + k0 + colh,
               (char*)Bs + (doff - lane * 16));
    }
    if (INPROJ) {
#pragma unroll
      for (int i = 0; i < 4; i++) {
        const float4 f0 = *(const float4*)(ap + k0 + i * 8);
        const float4 f1 = *(const float4*)(ap + k0 + i * 8 + 4);
        half8v hv;
        hv[0] = (_Float16)f0.x; hv[1] = (_Float16)f0.y;
        hv[2] = (_Float16)f0.z; hv[3] = (_Float16)f0.w;
        hv[4] = (_Float16)f1.x; hv[5] = (_Float16)f1.y;
        hv[6] = (_Float16)f1.z; hv[7] = (_Float16)f1.w;
        *(half8v*)((char*)As + ar * 128 + ((acb + i * 16) ^ ar7)) = hv;
      }
    } else {
#pragma unroll
      for (int i = 0; i < 4; i++) {
        const int doff = w * 4096 + i * 1024 + lane * 16;
        const int row = doff >> 7;
        const int colh = ((doff & 127) ^ ((row & 7) << 4)) >> 1;
        gl_lds16(A16 + (size_t)(bm + row) * EMB + k0 + colh,
                 (char*)As + (doff - lane * 16));
      }
    }
    __syncthreads();

#pragma unroll
    for (int kk = 0; kk < 2; kk++) {
      half8v af[4], bf[NF];
      const int c0 = (kk * 64 + g * 8) ^ swz;
      const int c1 = (kk * 64 + 32 + g * 8) ^ swz;
#pragma unroll
      for (int m = 0; m < 4; m++) {
        const char* rb = (const char*)As + (wr + m * 16 + r16) * 128;
        af[m] = join44(*(const half4v*)(rb + c0), *(const half4v*)(rb + c1));
      }
#pragma unroll
      for (int n = 0; n < NF; n++) {
        const char* rb = (const char*)Bs + (wc + n * 16 + r16) * 128;
        bf[n] = join44(*(const half4v*)(rb + c0), *(const half4v*)(rb + c1));
      }
#pragma unroll
      for (int m = 0; m < 4; m++)
#pragma unroll
        for (int n = 0; n < NF; n++)
          acc[m][n] = __builtin_amdgcn_mfma_f32_16x16x32_f16(af[m], bf[n],
                                                             acc[m][n], 0, 0, 0);
    }
  }

  // epilogue. C/D frag: row = 4*(lane>>4)+reg, col = lane&15 (verified).
#pragma unroll
  for (int m = 0; m < 4; m++) {
    const int grow = bm + wr + m * 16 + g * 4;
#pragma unroll
    for (int n = 0; n < NF; n++) {
      const int gcol = bn + wc + n * 16 + r16;
      const float bc = bias[gcol];
#pragma unroll
      for (int r = 0; r < 4; r++) {
        const float v = acc[m][n][r] + bc;
        const int rr = grow + r;
        if (INPROJ) {
          // rr = s*BATCH + b ; gcol = h*64 + d  ->  (B,H,S,HD) f16
          const int s = rr >> 1, b = rr & 1;
          const int hh = gcol >> 6, d = gcol & 63;
          ((_Float16*)dstbase + (size_t)z * MROWS * EMB)
              [(((size_t)(b * NH + hh)) * S_LEN + s) * HDIM + d] = (_Float16)v;
        } else {
          ((float*)dstbase)[(size_t)rr * EMB + gcol] = v;
        }
      }
    }
  }
}

// ---------------------------------------------------------------------------
// Row L2-normalize (per 64-wide head row), optionally folding 1/clip(tau,.01).
// ---------------------------------------------------------------------------
__global__ __launch_bounds__(256) void norm_rows(_Float16* __restrict__ buf,
                                                 const float* __restrict__ tau,
                                                 int use_tau) {
  const int row = blockIdx.x * 4 + (threadIdx.x >> 6);
  const int lane = threadIdx.x & 63;
  const size_t idx = (size_t)row * HDIM + lane;
  const float v = (float)buf[idx];
  float ss = v * v;
#pragma unroll
  for (int m = 1; m < 64; m <<= 1) ss += __shfl_xor(ss, m, 64);
  float scale = 1.0f / fmaxf(sqrtf(ss), 1e-12f);
  if (use_tau) {
    const int h = (row >> 11) & (NH - 1);  // row = (b*NH+h)*S + s
    scale *= 1.0f / fmaxf(tau[h], 0.01f);
  }
  buf[idx] = (_Float16)(v * scale);
}

// ---------------------------------------------------------------------------
// Flash attention, swapped-QK^T form. One (b,h) head + 128-row Q tile per
// block; 4 waves x 32 q-rows (2 q-groups of 16). KV tile = 64.
// S^T = mfma(K, Q): lane holds S[q=lane&15][key=16n+4g+r] -> softmax is
// 16 lane-local values + shfl_xor(16,32); the exp'd fragment feeds PV's
// A-operand directly (no LDS round-trip for P).
// ---------------------------------------------------------------------------
__global__ __launch_bounds__(256) void attn_fwd(const _Float16* __restrict__ qn,
                                                const _Float16* __restrict__ kn,
                                                const _Float16* __restrict__ vv,
                                                _Float16* __restrict__ outp) {
  __shared__ __align__(16) _Float16 Kt[64][72];  // [key][d]
  __shared__ __align__(16) _Float16 Vt[64][72];  // [d][key] (V^T)

  const int tid = threadIdx.x, lane = tid & 63, w = tid >> 6;
  const int g = lane >> 4, r16 = lane & 15;
  const int bh = blockIdx.y, b = bh >> 4, h = bh & 15;
  const int q0 = blockIdx.x * 128;
  const size_t hb = (size_t)bh * S_LEN * HDIM;
  const _Float16* Q = qn + hb;
  const _Float16* Kp = kn + hb;
  const _Float16* Vp = vv + hb;

  // Q as B-operand fragments: qf[qg][kk], lane holds Q[q=r16][d]
  half8v qf[2][2];
#pragma unroll
  for (int qg = 0; qg < 2; qg++) {
    const _Float16* qp = Q + (size_t)(q0 + w * 32 + qg * 16 + r16) * HDIM;
#pragma unroll
    for (int kk = 0; kk < 2; kk++)
      qf[qg][kk] = join44(*(const half4v*)(qp + kk * 32 + 4 * g),
                          *(const half4v*)(qp + kk * 32 + 16 + 4 * g));
  }

  f32x4 o[2][4];
#pragma unroll
  for (int qg = 0; qg < 2; qg++)
#pragma unroll
    for (int n = 0; n < 4; n++) o[qg][n] = (f32x4){0.f, 0.f, 0.f, 0.f};
  float mr[2] = {-1e30f, -1e30f};
  float lr[2] = {0.f, 0.f};

  const int skey = tid >> 2, sd = (tid & 3) * 16;  // K staging coords

  for (int t0 = 0; t0 < S_LEN; t0 += 64) {
    __syncthreads();
    {
      // K tile row-major (coalesced b128 loads + b128 LDS writes)
      const _Float16* kp = Kp + (size_t)(t0 + skey) * HDIM + sd;
      *(half8v*)&Kt[skey][sd] = *(const half8v*)kp;
      *(half8v*)&Kt[skey][sd + 8] = *(const half8v*)(kp + 8);
      // V^T tile: 8 coalesced scalar loads per key-octet -> one b128 write
#pragma unroll
      for (int c = 0; c < 2; c++) {
        const int o8 = w + c * 4;
        const _Float16* vp = Vp + (size_t)(t0 + o8 * 8) * HDIM + lane;
        half8v vcol;
#pragma unroll
        for (int j = 0; j < 8; j++) vcol[j] = vp[j * HDIM];
        *(half8v*)&Vt[lane][o8 * 8] = vcol;
      }
    }
    __syncthreads();

    // S^T = K @ Q^T : sv[qg][n] covers keys 16n..16n+15 x 16 q
    f32x4 sv[2][4];
#pragma unroll
    for (int qg = 0; qg < 2; qg++)
#pragma unroll
      for (int n = 0; n < 4; n++) sv[qg][n] = (f32x4){0.f, 0.f, 0.f, 0.f};
    __builtin_amdgcn_s_setprio(1);
#pragma unroll
    for (int n = 0; n < 4; n++) {
      const _Float16* kb = &Kt[n * 16 + r16][0];
      const half8v kf0 = join44(*(const half4v*)(kb + 4 * g),
                                *(const half4v*)(kb + 16 + 4 * g));
      const half8v kf1 = join44(*(const half4v*)(kb + 32 + 4 * g),
                                *(const half4v*)(kb + 48 + 4 * g));
#pragma unroll
      for (int qg = 0; qg < 2; qg++) {
        sv[qg][n] = __builtin_amdgcn_mfma_f32_16x16x32_f16(kf0, qf[qg][0],
                                                           sv[qg][n], 0, 0, 0);
        sv[qg][n] = __builtin_amdgcn_mfma_f32_16x16x32_f16(kf1, qf[qg][1],
                                                           sv[qg][n], 0, 0, 0);
      }
    }
    __builtin_amdgcn_s_setprio(0);

    // online softmax, state per lane for q = r16
    half8v pf[2][2];
#pragma unroll
    for (int qg = 0; qg < 2; qg++) {
      float pm = -1e30f;
#pragma unroll
      for (int n = 0; n < 4; n++)
#pragma unroll
        for (int r = 0; r < 4; r++) pm = fmaxf(pm, sv[qg][n][r]);
      pm = fmaxf(pm, __shfl_xor(pm, 16, 64));
      pm = fmaxf(pm, __shfl_xor(pm, 32, 64));
      const float mn = fmaxf(mr[qg], pm);
      const float scq = __expf(mr[qg] - mn);
      mr[qg] = mn;
      float ps = 0.f;
#pragma unroll
      for (int n = 0; n < 4; n++)
#pragma unroll
        for (int r = 0; r < 4; r++) {
          const float p = __expf(sv[qg][n][r] - mn);
          sv[qg][n][r] = p;
          ps += p;
        }
      ps += __shfl_xor(ps, 16, 64);
      ps += __shfl_xor(ps, 32, 64);
      lr[qg] = lr[qg] * scq + ps;
      // rescale o: o rows are q = 4g+r -> fetch that row's scale
      float srow[4];
#pragma unroll
      for (int r = 0; r < 4; r++) srow[r] = __shfl(scq, 4 * g + r, 64);
#pragma unroll
      for (int n = 0; n < 4; n++)
#pragma unroll
        for (int r = 0; r < 4; r++) o[qg][n][r] *= srow[r];
      // P fragment (A-operand of PV) straight from registers
#pragma unroll
      for (int kk = 0; kk < 2; kk++) {
        half8v t;
#pragma unroll
        for (int j = 0; j < 8; j++)
          t[j] = (_Float16)sv[qg][2 * kk + (j >> 2)][j & 3];
        pf[qg][kk] = t;
      }
    }

    // O += P @ V
    __builtin_amdgcn_s_setprio(1);
#pragma unroll
    for (int n = 0; n < 4; n++) {
      const _Float16* vb = &Vt[n * 16 + r16][0];
      const half8v vf0 = join44(*(const half4v*)(vb + 4 * g),
                                *(const half4v*)(vb + 16 + 4 * g));
      const half8v vf1 = join44(*(const half4v*)(vb + 32 + 4 * g),
                                *(const half4v*)(vb + 48 + 4 * g));
#pragma unroll
      for (int qg = 0; qg < 2; qg++) {
        o[qg][n] = __builtin_amdgcn_mfma_f32_16x16x32_f16(pf[qg][0], vf0,
                                                          o[qg][n], 0, 0, 0);
        o[qg][n] = __builtin_amdgcn_mfma_f32_16x16x32_f16(pf[qg][1], vf1,
                                                          o[qg][n], 0, 0, 0);
      }
    }
    __builtin_amdgcn_s_setprio(0);
  }

  // epilogue: out rows q = 4g+r, cols d = 16n+r16; write f16 (S,B,E)
#pragma unroll
  for (int qg = 0; qg < 2; qg++) {
    const float li = 1.0f / lr[qg];
    float lrow[4];
#pragma unroll
    for (int r = 0; r < 4; r++) lrow[r] = __shfl(li, 4 * g + r, 64);
#pragma unroll
    for (int n = 0; n < 4; n++) {
      const int e = h * HDIM + n * 16 + r16;
#pragma unroll
      for (int r = 0; r < 4; r++) {
        const int srow = q0 + w * 32 + qg * 16 + 4 * g + r;
        outp[((size_t)srow * BATCH + b) * EMB + e] =
            (_Float16)(o[qg][n][r] * lrow[r]);
      }
    }
  }
}

// ---------------------------------------------------------------------------
extern "C" void kernel_launch(void* const* d_in, const int* in_sizes, int n_in,
                              void* d_out, int out_size, void* d_ws,
                              size_t ws_size, hipStream_t stream) {
  const float* query = (const float*)d_in[0];
  const float* key   = (const float*)d_in[1];
  const float* value = (const float*)d_in[2];
  const float* ipw   = (const float*)d_in[3];  // (3E, E)
  const float* ipb   = (const float*)d_in[4];  // (3E,)
  const float* opw   = (const float*)d_in[5];  // (E, E)
  const float* opb   = (const float*)d_in[6];  // (E,)
  const float* tau   = (const float*)d_in[7];  // (1,H,1,1)

  // workspace: qbuf/kbuf/vbuf (B,H,S,HD) f16, abuf (S,B,E) f16, weights f16
  _Float16* qbuf  = (_Float16*)d_ws;
  _Float16* kbuf  = qbuf + (size_t)MROWS * EMB;
  _Float16* vbuf  = kbuf + (size_t)MROWS * EMB;
  _Float16* abuf  = vbuf + (size_t)MROWS * EMB;
  _Float16* ipw16 = abuf + (size_t)MROWS * EMB;
  _Float16* opw16 = ipw16 + (size_t)3 * EMB * EMB;

  cvt4<<<(3 * EMB * EMB / 4 + 255) / 256, 256, 0, stream>>>(ipw, ipw16,
                                                            3 * EMB * EMB / 4);
  cvt4<<<(EMB * EMB / 4 + 255) / 256, 256, 0, stream>>>(opw, opw16,
                                                        EMB * EMB / 4);

  // fused q/k/v in-projection: grid.z selects input & weight slice
  gemm_f16<1, 128><<<dim3(EMB / 128, MROWS / 128, 3), 256, 0, stream>>>(
      query, key, value, nullptr, ipw16, ipb, qbuf);

  const int nrows = BATCH * NH * S_LEN;  // 65536
  norm_rows<<<nrows / 4, 256, 0, stream>>>(qbuf, tau, 1);
  norm_rows<<<nrows / 4, 256, 0, stream>>>(kbuf, tau, 0);

  attn_fwd<<<dim3(S_LEN / 128, BATCH * NH), 256, 0, stream>>>(qbuf, kbuf, vbuf,
                                                              abuf);

  gemm_f16<0, 64><<<dim3(EMB / 64, MROWS / 128, 1), 256, 0, stream>>>(
      nullptr, nullptr, nullptr, abuf, opw16, opb, d_out);
}

// Round 4
// 278.752 us; speedup vs baseline: 1.5231x; 1.0871x over previous
//
#include <hip/hip_runtime.h>
#include <hip/hip_bf16.h>

// Problem constants (S, B, E, H) = (2048, 2, 1024, 16), HD = 64
#define S_LEN 2048
#define BATCH 2
#define EMB   1024
#define NH    16
#define HDIM  64
#define MROWS (S_LEN * BATCH)   // 4096 rows of the (S,B,E) matrices

typedef _Float16 half4v __attribute__((ext_vector_type(4)));
typedef _Float16 half8v __attribute__((ext_vector_type(8)));
typedef float    f32x4  __attribute__((ext_vector_type(4)));

static __device__ __forceinline__ half8v join44(half4v lo, half4v hi) {
  half8v r;
  r[0] = lo[0]; r[1] = lo[1]; r[2] = lo[2]; r[3] = lo[3];
  r[4] = hi[0]; r[5] = hi[1]; r[6] = hi[2]; r[7] = hi[3];
  return r;
}

// async global->LDS, 16B per lane. dst = wave-uniform base (HW adds lane*16).
static __device__ __forceinline__ void gl_lds16(const _Float16* src, void* dst) {
  __builtin_amdgcn_global_load_lds(
      (const __attribute__((address_space(1))) void*)src,
      (__attribute__((address_space(3))) void*)dst, 16, 0, 0);
}

// ---------------------------------------------------------------------------
// Fused f32 -> f16 convert of all five arrays (q, k, v, ipw, opw).
// Boundaries in float4 units (compile-time): 1048576 each for q/k/v,
// 786432 for ipw, 262144 for opw; total 4194304 float4s.
// ---------------------------------------------------------------------------
__global__ __launch_bounds__(256) void cvt_all(
    const float* __restrict__ q, const float* __restrict__ k,
    const float* __restrict__ v, const float* __restrict__ ipw,
    const float* __restrict__ opw, _Float16* __restrict__ qo,
    _Float16* __restrict__ ko, _Float16* __restrict__ vo,
    _Float16* __restrict__ ipo, _Float16* __restrict__ opo) {
  const int i = blockIdx.x * 256 + threadIdx.x;
  const float* src;
  _Float16* dst;
  int off;
  if (i < 1048576) { src = q; dst = qo; off = i; }
  else if (i < 2097152) { src = k; dst = ko; off = i - 1048576; }
  else if (i < 3145728) { src = v; dst = vo; off = i - 2097152; }
  else if (i < 3932160) { src = ipw; dst = ipo; off = i - 3145728; }
  else { src = opw; dst = opo; off = i - 3932160; }
  const float4 f = ((const float4*)src)[off];
  half4v hv;
  hv[0] = (_Float16)f.x; hv[1] = (_Float16)f.y;
  hv[2] = (_Float16)f.z; hv[3] = (_Float16)f.w;
  ((half4v*)dst)[off] = hv;
}

// ---------------------------------------------------------------------------
// Stage one 128x64-half tile (16KB) via 4 gload_lds per wave, T2 XOR swizzle
// applied to the GLOBAL source granule (rule 21: linear LDS dest).
// gsrc = base of tile (row stride 1024 halves).
// ---------------------------------------------------------------------------
static __device__ __forceinline__ void stage_tile(const _Float16* gsrc,
                                                  _Float16* lds, int w,
                                                  int lane) {
#pragma unroll
  for (int i = 0; i < 4; i++) {
    const int base = (w << 12) + (i << 10);
    const int doff = base + (lane << 4);
    const int row = doff >> 7;
    const int colb = (doff & 127) ^ ((row & 7) << 4);
    gl_lds16(gsrc + (size_t)row * EMB + (colb >> 1), (char*)lds + base);
  }
}

// ---------------------------------------------------------------------------
// TN GEMM: C[M,N] = A[M,K] @ W[N,K]^T + bias[N]. All-f16 operands, K=1024,
// tile 128x128, BK=64, double-buffered (T3 minimal 2-phase), XCD-swizzled.
// MODE 1 (in-proj): z in [0,3) selects A/W/bias slice; epilogue does per-head
//   L2-normalize (z<2) and folds 1/clip(tau,.01) (z==0); f16 (B,H,S,HD) out.
// MODE 0 (out-proj): f32 row-major out.
// ---------------------------------------------------------------------------
template <int MODE>
__global__ __launch_bounds__(256, 2) void gemm16(
    const _Float16* __restrict__ Abase, const _Float16* __restrict__ Wbase,
    const float* __restrict__ ball, const float* __restrict__ tau,
    void* __restrict__ dstv) {
  __shared__ __align__(16) _Float16 As[2][128 * 64];
  __shared__ __align__(16) _Float16 Bs[2][128 * 64];

  const int tid = threadIdx.x, lane = tid & 63, w = tid >> 6;
  const int g = lane >> 4, r16 = lane & 15;

  // XCD-aware bijective swizzle of the flat block id
  constexpr int NWG = MODE ? 768 : 256;
  constexpr int CHUNK = NWG / 8;
  int flat = blockIdx.x + 8 * (blockIdx.y + 32 * blockIdx.z);
  flat = (flat & 7) * CHUNK + (flat >> 3);
  const int bx = flat & 7;
  const int by = (flat >> 3) & 31;
  const int bz = MODE ? (flat >> 8) : 0;

  const int bm = by * 128, bn = bx * 128;
  const int wr = (w >> 1) * 64, wc = (w & 1) * 64;
  const int swz = (r16 & 7) << 4;

  const _Float16* A = Abase + (MODE ? (size_t)bz * MROWS * EMB : 0);
  const _Float16* W = Wbase + (MODE ? (size_t)bz * EMB * EMB : 0);
  const float* bias = ball + (MODE ? bz * EMB : 0);

  f32x4 acc[4][4];
#pragma unroll
  for (int m = 0; m < 4; m++)
#pragma unroll
    for (int n = 0; n < 4; n++) acc[m][n] = (f32x4){0.f, 0.f, 0.f, 0.f};

  const _Float16* Ap = A + (size_t)bm * EMB;
  const _Float16* Wp = W + (size_t)bn * EMB;

  // prologue: stage K-tile 0 into buffer 0
  stage_tile(Ap, As[0], w, lane);
  stage_tile(Wp, Bs[0], w, lane);
  __syncthreads();

  int cur = 0;
  for (int t = 0; t < 16; t++) {
    if (t < 15) {
      stage_tile(Ap + (t + 1) * 64, As[cur ^ 1], w, lane);
      stage_tile(Wp + (t + 1) * 64, Bs[cur ^ 1], w, lane);
    }
#pragma unroll
    for (int kk = 0; kk < 2; kk++) {
      half8v af[4], bf[4];
      const int cA = kk * 64 + (g << 3);
#pragma unroll
      for (int m = 0; m < 4; m++) {
        const char* rb = (const char*)(As[cur]) + ((wr + m * 16 + r16) << 7);
        af[m] = join44(*(const half4v*)(rb + (cA ^ swz)),
                       *(const half4v*)(rb + ((cA + 32) ^ swz)));
      }
#pragma unroll
      for (int n = 0; n < 4; n++) {
        const char* rb = (const char*)(Bs[cur]) + ((wc + n * 16 + r16) << 7);
        bf[n] = join44(*(const half4v*)(rb + (cA ^ swz)),
                       *(const half4v*)(rb + ((cA + 32) ^ swz)));
      }
#pragma unroll
      for (int m = 0; m < 4; m++)
#pragma unroll
        for (int n = 0; n < 4; n++)
          acc[m][n] = __builtin_amdgcn_mfma_f32_16x16x32_f16(af[m], bf[n],
                                                             acc[m][n], 0, 0, 0);
    }
    __syncthreads();  // drains vmcnt(0): next buffer ready
    cur ^= 1;
  }

  // epilogue. C/D frag: row = 4*(lane>>4)+reg, col = lane&15 (verified).
  float bcol[4];
#pragma unroll
  for (int n = 0; n < 4; n++) bcol[n] = bias[bn + wc + n * 16 + r16];

  if (MODE == 1) {
    // this wave's 4 n-frags cover one full 64-wide head row
    const int hw = (bn + wc) >> 6;
    const float tsc = (bz == 0) ? 1.0f / fmaxf(tau[hw], 0.01f) : 1.0f;
    _Float16* dst = (_Float16*)dstv + (size_t)bz * MROWS * EMB;
#pragma unroll
    for (int m = 0; m < 4; m++)
#pragma unroll
      for (int r = 0; r < 4; r++) {
        float v[4], ss = 0.f;
#pragma unroll
        for (int n = 0; n < 4; n++) {
          v[n] = acc[m][n][r] + bcol[n];
          ss += v[n] * v[n];
        }
        ss += __shfl_xor(ss, 1, 64);
        ss += __shfl_xor(ss, 2, 64);
        ss += __shfl_xor(ss, 4, 64);
        ss += __shfl_xor(ss, 8, 64);
        const float sc = (bz == 2) ? 1.0f : tsc / fmaxf(sqrtf(ss), 1e-12f);
        const int rr = bm + wr + m * 16 + g * 4 + r;
        const int s = rr >> 1, bb = rr & 1;
        const size_t rowb = (((size_t)(bb * NH + hw)) * S_LEN + s) * HDIM;
#pragma unroll
        for (int n = 0; n < 4; n++)
          dst[rowb + n * 16 + r16] = (_Float16)(v[n] * sc);
      }
  } else {
#pragma unroll
    for (int m = 0; m < 4; m++) {
      const int grow = bm + wr + m * 16 + g * 4;
#pragma unroll
      for (int n = 0; n < 4; n++) {
        const int gcol = bn + wc + n * 16 + r16;
#pragma unroll
        for (int r = 0; r < 4; r++)
          ((float*)dstv)[(size_t)(grow + r) * EMB + gcol] =
              acc[m][n][r] + bcol[n];
      }
    }
  }
}

// ---------------------------------------------------------------------------
// Flash attention, swapped-QK^T, double-buffered K/V (one barrier per tile),
// T14 issue-early/write-late for the V^T reg-stage, XOR-swizzled [64][64]
// K/V tiles, XCD-swizzled grid. 4 waves x 32 q-rows, KV tile = 64.
// ---------------------------------------------------------------------------
__global__ __launch_bounds__(256) void attn_fwd(const _Float16* __restrict__ qn,
                                                const _Float16* __restrict__ kn,
                                                const _Float16* __restrict__ vv,
                                                _Float16* __restrict__ outp) {
  __shared__ __align__(16) _Float16 Kt[2][64 * 64];  // [key][d], swizzled
  __shared__ __align__(16) _Float16 Vt[2][64 * 64];  // [d][key], swizzled

  const int tid = threadIdx.x, lane = tid & 63, w = tid >> 6;
  const int g = lane >> 4, r16 = lane & 15;
  const int s7 = (r16 & 7) << 4;

  // XCD swizzle: nwg = 512, 16 q-tiles (x) fastest
  int flat = blockIdx.x + (blockIdx.y << 4);
  flat = (flat & 7) * 64 + (flat >> 3);
  const int bx = flat & 15, bh = flat >> 4;
  const int b = bh >> 4, h = bh & 15;
  const int q0 = bx * 128;

  const size_t hb = (size_t)bh * S_LEN * HDIM;
  const _Float16* Q = qn + hb;
  const _Float16* Kp = kn + hb;
  const _Float16* Vp = vv + hb;

  // Q as B-operand fragments: qf[qg][kk], lane holds Q[q=r16][d]
  half8v qf[2][2];
#pragma unroll
  for (int qg = 0; qg < 2; qg++) {
    const _Float16* qp = Q + (size_t)(q0 + w * 32 + qg * 16 + r16) * HDIM;
#pragma unroll
    for (int kk = 0; kk < 2; kk++)
      qf[qg][kk] = join44(*(const half4v*)(qp + kk * 32 + 4 * g),
                          *(const half4v*)(qp + kk * 32 + 16 + 4 * g));
  }

  f32x4 o[2][4];
#pragma unroll
  for (int qg = 0; qg < 2; qg++)
#pragma unroll
    for (int n = 0; n < 4; n++) o[qg][n] = (f32x4){0.f, 0.f, 0.f, 0.f};
  float mr[2] = {-1e30f, -1e30f};
  float lr[2] = {0.f, 0.f};

  // ---- staging helpers (lambdas) ----
  auto stage_k = [&](int buf, int t0) {
#pragma unroll
    for (int i = 0; i < 2; i++) {
      const int base = (w << 11) + (i << 10);
      const int doff = base + (lane << 4);
      const int row = doff >> 7;
      const int colb = (doff & 127) ^ ((row & 7) << 4);
      gl_lds16(Kp + (size_t)(t0 + row) * HDIM + (colb >> 1),
               (char*)(Kt[buf]) + base);
    }
  };
  auto vload = [&](half8v& v0, half8v& v1, int t0) {
    const _Float16* vp0 = Vp + (size_t)(t0 + w * 8) * HDIM + lane;
    const _Float16* vp1 = Vp + (size_t)(t0 + (w + 4) * 8) * HDIM + lane;
#pragma unroll
    for (int j = 0; j < 8; j++) {
      v0[j] = vp0[j * HDIM];
      v1[j] = vp1[j * HDIM];
    }
  };
  auto vwrite = [&](int buf, half8v v0, half8v v1) {
    char* vb = (char*)(Vt[buf]) + (lane << 7);
    const int lw = (lane & 7) << 4;
    *(half8v*)(vb + ((w << 4) ^ lw)) = v0;
    *(half8v*)(vb + (((w + 4) << 4) ^ lw)) = v1;
  };

  // prologue: tile 0 into buffer 0
  stage_k(0, 0);
  {
    half8v v0, v1;
    vload(v0, v1, 0);
    vwrite(0, v0, v1);
  }
  __syncthreads();

  int cur = 0;
  for (int t0 = 0; t0 < S_LEN; t0 += 64) {
    const int nxt = cur ^ 1;
    const bool more = (t0 + 64) < S_LEN;
    half8v vr0, vr1;
    if (more) {
      stage_k(nxt, t0 + 64);   // async into other buffer
      vload(vr0, vr1, t0 + 64);  // issue early; consumed after compute
    }

    // ---- S^T = K @ Q^T from Kt[cur]
    f32x4 sv[2][4];
#pragma unroll
    for (int qg = 0; qg < 2; qg++)
#pragma unroll
      for (int n = 0; n < 4; n++) sv[qg][n] = (f32x4){0.f, 0.f, 0.f, 0.f};
    __builtin_amdgcn_s_setprio(1);
#pragma unroll
    for (int n = 0; n < 4; n++) {
      const char* kb = (const char*)(Kt[cur]) + ((n * 16 + r16) << 7);
      const half8v kf0 = join44(*(const half4v*)(kb + ((8 * g) ^ s7)),
                                *(const half4v*)(kb + ((8 * g + 32) ^ s7)));
      const half8v kf1 = join44(*(const half4v*)(kb + ((8 * g + 64) ^ s7)),
                                *(const half4v*)(kb + ((8 * g + 96) ^ s7)));
#pragma unroll
      for (int qg = 0; qg < 2; qg++) {
        sv[qg][n] = __builtin_amdgcn_mfma_f32_16x16x32_f16(kf0, qf[qg][0],
                                                           sv[qg][n], 0, 0, 0);
        sv[qg][n] = __builtin_amdgcn_mfma_f32_16x16x32_f16(kf1, qf[qg][1],
                                                           sv[qg][n], 0, 0, 0);
      }
    }
    __builtin_amdgcn_s_setprio(0);

    // ---- online softmax (state per lane for q = r16)
    half8v pf[2][2];
#pragma unroll
    for (int qg = 0; qg < 2; qg++) {
      float pm = -1e30f;
#pragma unroll
      for (int n = 0; n < 4; n++)
#pragma unroll
        for (int r = 0; r < 4; r++) pm = fmaxf(pm, sv[qg][n][r]);
      pm = fmaxf(pm, __shfl_xor(pm, 16, 64));
      pm = fmaxf(pm, __shfl_xor(pm, 32, 64));
      const float mn = fmaxf(mr[qg], pm);
      const float scq = __expf(mr[qg] - mn);
      mr[qg] = mn;
      float ps = 0.f;
#pragma unroll
      for (int n = 0; n < 4; n++)
#pragma unroll
        for (int r = 0; r < 4; r++) {
          const float p = __expf(sv[qg][n][r] - mn);
          sv[qg][n][r] = p;
          ps += p;
        }
      ps += __shfl_xor(ps, 16, 64);
      ps += __shfl_xor(ps, 32, 64);
      lr[qg] = lr[qg] * scq + ps;
      float srow[4];
#pragma unroll
      for (int r = 0; r < 4; r++) srow[r] = __shfl(scq, 4 * g + r, 64);
#pragma unroll
      for (int n = 0; n < 4; n++)
#pragma unroll
        for (int r = 0; r < 4; r++) o[qg][n][r] *= srow[r];
#pragma unroll
      for (int kk = 0; kk < 2; kk++) {
        half8v t;
#pragma unroll
        for (int j = 0; j < 8; j++)
          t[j] = (_Float16)sv[qg][2 * kk + (j >> 2)][j & 3];
        pf[qg][kk] = t;
      }
    }

    // ---- O += P @ V from Vt[cur]
    __builtin_amdgcn_s_setprio(1);
#pragma unroll
    for (int n = 0; n < 4; n++) {
      const char* vb = (const char*)(Vt[cur]) + ((n * 16 + r16) << 7);
      const half8v vf0 = join44(*(const half4v*)(vb + ((8 * g) ^ s7)),
                                *(const half4v*)(vb + ((8 * g + 32) ^ s7)));
      const half8v vf1 = join44(*(const half4v*)(vb + ((8 * g + 64) ^ s7)),
                                *(const half4v*)(vb + ((8 * g + 96) ^ s7)));
#pragma unroll
      for (int qg = 0; qg < 2; qg++) {
        o[qg][n] = __builtin_amdgcn_mfma_f32_16x16x32_f16(pf[qg][0], vf0,
                                                          o[qg][n], 0, 0, 0);
        o[qg][n] = __builtin_amdgcn_mfma_f32_16x16x32_f16(pf[qg][1], vf1,
                                                          o[qg][n], 0, 0, 0);
      }
    }
    __builtin_amdgcn_s_setprio(0);

    if (more) vwrite(nxt, vr0, vr1);  // write-late (T14)
    __syncthreads();                  // drains vmcnt for stage_k too
    cur = nxt;
  }

  // epilogue: out rows q = 4g+r, cols d = 16n+r16; write f16 (S,B,E)
#pragma unroll
  for (int qg = 0; qg < 2; qg++) {
    const float li = 1.0f / lr[qg];
    float lrow[4];
#pragma unroll
    for (int r = 0; r < 4; r++) lrow[r] = __shfl(li, 4 * g + r, 64);
#pragma unroll
    for (int n = 0; n < 4; n++) {
      const int e = h * HDIM + n * 16 + r16;
#pragma unroll
      for (int r = 0; r < 4; r++) {
        const int srow = q0 + w * 32 + qg * 16 + 4 * g + r;
        outp[((size_t)srow * BATCH + b) * EMB + e] =
            (_Float16)(o[qg][n][r] * lrow[r]);
      }
    }
  }
}

// ---------------------------------------------------------------------------
extern "C" void kernel_launch(void* const* d_in, const int* in_sizes, int n_in,
                              void* d_out, int out_size, void* d_ws,
                              size_t ws_size, hipStream_t stream) {
  const float* query = (const float*)d_in[0];
  const float* key   = (const float*)d_in[1];
  const float* value = (const float*)d_in[2];
  const float* ipw   = (const float*)d_in[3];  // (3E, E)
  const float* ipb   = (const float*)d_in[4];  // (3E,)
  const float* opw   = (const float*)d_in[5];  // (E, E)
  const float* opb   = (const float*)d_in[6];  // (E,)
  const float* tau   = (const float*)d_in[7];  // (1,H,1,1)

  // workspace (f16): qin|kin|vin, ipw16, opw16, qbuf|kbuf|vbuf; abuf = qin
  _Float16* qin   = (_Float16*)d_ws;
  _Float16* kin   = qin + (size_t)MROWS * EMB;
  _Float16* vin   = kin + (size_t)MROWS * EMB;
  _Float16* ipw16 = vin + (size_t)MROWS * EMB;
  _Float16* opw16 = ipw16 + (size_t)3 * EMB * EMB;
  _Float16* qbuf  = opw16 + (size_t)EMB * EMB;
  _Float16* kbuf  = qbuf + (size_t)MROWS * EMB;
  _Float16* vbuf  = kbuf + (size_t)MROWS * EMB;
  _Float16* abuf  = qin;  // qin dead after in-proj

  cvt_all<<<16384, 256, 0, stream>>>(query, key, value, ipw, opw, qin, kin,
                                     vin, ipw16, opw16);

  // fused q/k/v in-projection + per-head L2 norm + tau fold
  gemm16<1><<<dim3(8, 32, 3), 256, 0, stream>>>(qin, ipw16, ipb, tau, qbuf);

  attn_fwd<<<dim3(16, 32), 256, 0, stream>>>(qbuf, kbuf, vbuf, abuf);

  gemm16<0><<<dim3(8, 32, 1), 256, 0, stream>>>(abuf, opw16, opb, nullptr,
                                                d_out);
}